// Round 3
// baseline (3201.168 us; speedup 1.0000x reference)
//
#include <hip/hip_runtime.h>
#include <math.h>

typedef _Float16 h2_t  __attribute__((ext_vector_type(2)));
typedef _Float16 h4_t  __attribute__((ext_vector_type(4)));
typedef _Float16 h8_t  __attribute__((ext_vector_type(8)));
typedef float    f4_t  __attribute__((ext_vector_type(4)));

#define T_ 512
#define B_ 64
#define E_ 256
#define H_ 256
#define G_ 1024   // 4*H
#define K_ 16
#define NEG_ (-10000.0f)
#define START_ 14
#define STOP_ 15

// ---------------------------------------------------------------------------
// Prep: pack all weights to fp16 in the layouts the hot kernels want.
//  wreg3: A-fragments for the recurrent MFMA GEMM.
//         h8 index = (((dir*32 + j)*2 + mt)*8 + kt)*64 + lane
//         lane holds A[m = mt*16 + (lane&15)][k = kt*32 + (lane>>4)*8 + e]
//         where weight row grow = (m>>3)*256 + 8*j + (m&7)      -> 1 MB
//  wih16: [dir][row 0..1023][k 0..255] fp16 copy of w_ih        -> 1 MB
// ---------------------------------------------------------------------------
__global__ __launch_bounds__(256)
void prep_weights(const float* __restrict__ w_hh_f,
                  const float* __restrict__ w_hh_b,
                  const float* __restrict__ w_ih_f,
                  const float* __restrict__ w_ih_b,
                  _Float16* __restrict__ wreg3,
                  _Float16* __restrict__ wih16)
{
    const int blk = blockIdx.x, tid = threadIdx.x;
    if (blk < 32) {                       // wreg3: 8192 threads x 8 h8
        int idx  = blk * 256 + tid;       // [dir][j][mt][lane]
        int dir  = idx >> 12;
        int j    = (idx >> 7) & 31;
        int mt   = (idx >> 6) & 1;
        int lane = idx & 63;
        int m_local = mt * 16 + (lane & 15);
        int grow = (m_local >> 3) * 256 + 8 * j + (m_local & 7);
        int k0   = (lane >> 4) * 8;
        const float* whh = dir ? w_hh_b : w_hh_f;
        h8_t* dstb = (h8_t*)wreg3;
        #pragma unroll
        for (int kt = 0; kt < 8; ++kt) {
            const float* src = whh + (size_t)grow * 256 + kt * 32 + k0;
            h8_t o;
            #pragma unroll
            for (int e = 0; e < 8; ++e) o[e] = (_Float16)src[e];
            dstb[((size_t)(idx >> 6) * 8 + kt) * 64 + lane] = o;
        }
    } else {                              // wih16: 65536 x h8
        int idx = (blk - 32) * 256 + tid;
        int dir = idx / 32768, rem = idx % 32768;
        const float* src = (dir ? w_ih_b : w_ih_f) + (size_t)rem * 8;
        _Float16* dst = wih16 + (size_t)idx * 8;
        #pragma unroll
        for (int i = 0; i < 8; ++i) dst[i] = (_Float16)src[i];
    }
}

// ---------------------------------------------------------------------------
// Kernel A: input-gate GEMM via f16 MFMA 16x16x32 (unchanged, proven).
// ---------------------------------------------------------------------------
__global__ __launch_bounds__(256)
void gates_mfma(const int* __restrict__ sentence,
                const float* __restrict__ emb,
                const _Float16* __restrict__ wih16,
                _Float16* __restrict__ gin_f,
                _Float16* __restrict__ gin_b)
{
    __shared__ _Float16 As[64 * 264];
    __shared__ _Float16 Bs[256 * 40];
    __shared__ int sidx[64];

    const int bm  = blockIdx.x;           // t
    const int dir = blockIdx.y;
    const int tid = threadIdx.x;

    const _Float16* __restrict__ wih = wih16 + (size_t)dir * 262144;
    _Float16* __restrict__ gout      = dir ? gin_b : gin_f;

    if (tid < 64) sidx[tid] = sentence[tid * T_ + bm];
    __syncthreads();

    {   // stage A (emb gather, fp32 -> fp16)
        const int r = tid & 63, kq = tid >> 6;
        const float4* src = (const float4*)(emb + (size_t)sidx[r] * 256 + kq * 64);
        _Float16* dst = As + r * 264 + kq * 64;
        #pragma unroll
        for (int c = 0; c < 8; ++c) {
            float4 v0 = src[2 * c], v1 = src[2 * c + 1];
            h8_t o;
            o[0] = (_Float16)v0.x; o[1] = (_Float16)v0.y;
            o[2] = (_Float16)v0.z; o[3] = (_Float16)v0.w;
            o[4] = (_Float16)v1.x; o[5] = (_Float16)v1.y;
            o[6] = (_Float16)v1.z; o[7] = (_Float16)v1.w;
            *(h8_t*)(dst + c * 8) = o;
        }
    }

    const int wave = tid >> 6, lane = tid & 63;
    const int l15 = lane & 15, quad = lane >> 4;

    for (int pass = 0; pass < 4; ++pass) {
        const int n0 = pass * 256;
        f4_t acc[16];
        #pragma unroll
        for (int nt = 0; nt < 16; ++nt) acc[nt] = (f4_t){0.f, 0.f, 0.f, 0.f};

        for (int kc = 0; kc < 8; ++kc) {
            __syncthreads();
            {
                const h8_t* bsrc = (const h8_t*)(wih + (size_t)(n0 + tid) * 256 + kc * 32);
                #pragma unroll
                for (int c = 0; c < 4; ++c)
                    *(h8_t*)(Bs + tid * 40 + c * 8) = bsrc[c];
            }
            __syncthreads();
            h8_t a = *(const h8_t*)(As + (wave * 16 + l15) * 264 + kc * 32 + quad * 8);
            #pragma unroll
            for (int nt = 0; nt < 16; ++nt) {
                h8_t b = *(const h8_t*)(Bs + (nt * 16 + l15) * 40 + quad * 8);
                acc[nt] = __builtin_amdgcn_mfma_f32_16x16x32_f16(a, b, acc[nt], 0, 0, 0);
            }
        }

        const size_t mbase = (size_t)bm * 64 + wave * 16 + quad * 4;
        #pragma unroll
        for (int nt = 0; nt < 16; ++nt) {
            const int col = n0 + nt * 16 + l15;
            #pragma unroll
            for (int r = 0; r < 4; ++r)
                gout[(mbase + r) * 1024 + col] = (_Float16)acc[nt][r];
        }
    }
}

// ---------------------------------------------------------------------------
// Kernel B: dataflow MFMA LSTM.
// 128 blocks = 4 groups (dir x batch-half) x 32 stripes. Block (g, j):
// M = 32 gate rows {gate*256 + 8j + 0..7}, N = 32 batch, K = 256 per step,
// as 32 x mfma_f32_16x16x32_f16 (4 waves x (mt,nt), 8 K-tiles each).
// A-fragments (weights): 8 h8 = 32 VGPRs/thread, loaded once — MFMA reads
// them from VGPR or AGPR natively, so allocator placement is irrelevant
// (fixes rounds 1-2's residency fight).
// h(s-1) all-gather: per-uint sentinel mailbox (0xFFFFFFFF = fp16 NaN pair,
// unreachable since |h|<1), relaxed agent-scope atomics. Producers never
// wait; consumers poll exactly the 16 uints they stage. B staged in LDS in
// fragment-linear order -> ds_read_b128 is lane-linear (conflict-free) and
// gather ds_writes are 2-way (free). 2 barriers/step.
// All 128 blocks co-resident (<=256 CUs) => spin cannot deadlock.
// ---------------------------------------------------------------------------
__global__ __launch_bounds__(256)
void lstm_gemm(const _Float16* __restrict__ gin_f,
               const _Float16* __restrict__ gin_b,
               const _Float16* __restrict__ wreg3,
               const float* __restrict__ b_f,
               const float* __restrict__ b_b,
               float* __restrict__ hf, float* __restrict__ hb,
               unsigned int* __restrict__ mail)
{
    __shared__ _Float16 hbufT[8192];      // 16 KB, fragment-linear B
    __shared__ float    gbuf[32 * 34];    // gates, padded rows (2-way banks)

    const int bid = blockIdx.x;
    const int g   = bid & 3;              // dir*2 + bhalf
    const int j   = bid >> 2;             // stripe 0..31
    const int dir = g >> 1, bh = g & 1;
    const int t   = threadIdx.x;
    const int wv  = t >> 6, lane = t & 63;
    const int mt  = wv >> 1, nt = wv & 1;
    const int l15 = lane & 15, quad = lane >> 4;

    const _Float16* __restrict__ gin  = dir ? gin_b : gin_f;
    const float*    __restrict__ bs   = dir ? b_b : b_f;
    float*          __restrict__ hout = dir ? hb : hf;

    // A-fragments (loop-invariant weights)
    const h8_t* wsrc = (const h8_t*)wreg3 +
                       ((((size_t)dir * 32 + j) * 2 + mt) * 8) * 64 + lane;
    h8_t Afr[8];
    #pragma unroll
    for (int kt = 0; kt < 8; ++kt) Afr[kt] = wsrc[kt * 64];

    // bias for this lane's 4 output rows (D rows m = mt*16 + quad*4 + r)
    const int mq = mt * 16 + quad * 4;
    const int growBase = (mq >> 3) * 256 + 8 * j + (mq & 7);
    const f4_t bias4 = *(const f4_t*)(bs + growBase);

    // per-step gin pointer (4 consecutive halves at growBase)
    const int sdir = dir ? -1 : 1;
    const int s0   = dir ? (T_ - 1) : 0;
    const _Float16* gp = gin + (size_t)s0 * 65536 +
                         (size_t)(bh * 32 + nt * 16 + l15) * 1024 + growBase;
    const long gstep = (long)sdir * 65536;

    // activation-side identity: h-row rl = t>>5, batch n = t&31
    const int n32 = t & 31;
    const int rl  = t >> 5;
    float* hp = hout + ((size_t)s0 * 64 + bh * 32 + n32) * 256 + 8 * j + rl;
    const long hstep = (long)sdir * (64 * 256);

    unsigned int* mailG = mail + (size_t)g * (512 * 128 * 32);
    const int kp0 = t >> 5;               // gather kpair base (0..7)
    unsigned int* hbU = (unsigned int*)hbufT;

    // zero-fill h(-1) via the gather addressing (covers all 4096 uints)
    #pragma unroll
    for (int i = 0; i < 16; ++i) {
        int kp  = kp0 + 8 * i;
        int off = (((n32 >> 4) * 8 + (kp >> 4)) * 4 + ((kp >> 2) & 3)) * 64 +
                  (n32 & 15) * 4 + (kp & 3);
        hbU[off] = 0u;
    }
    float c = 0.f;
    __syncthreads();

    for (int s = 0; s < T_; ++s) {
        h4_t g4 = *(const h4_t*)gp;       // issue early; hides under gather

        if (s > 0) {                      // gather h(s-1) from the group
            const unsigned int* pb = mailG + (size_t)(s - 1) * 4096 +
                                     kp0 * 32 + n32;
            unsigned int uv[16];
            #pragma unroll
            for (int i = 0; i < 16; ++i)
                uv[i] = __hip_atomic_load(pb + i * 256, __ATOMIC_RELAXED,
                                          __HIP_MEMORY_SCOPE_AGENT);
            #pragma unroll
            for (int i = 0; i < 16; ++i) {
                unsigned int u = uv[i];
                int guard = 0;
                while (u == 0xFFFFFFFFu && ++guard < (1 << 20))
                    u = __hip_atomic_load(pb + i * 256, __ATOMIC_RELAXED,
                                          __HIP_MEMORY_SCOPE_AGENT);
                int kp  = kp0 + 8 * i;
                int off = (((n32 >> 4) * 8 + (kp >> 4)) * 4 +
                           ((kp >> 2) & 3)) * 64 + (n32 & 15) * 4 + (kp & 3);
                hbU[off] = u;
            }
        }
        __syncthreads();                  // hbufT ready

        f4_t acc;
        acc[0] = bias4[0] + (float)g4[0];
        acc[1] = bias4[1] + (float)g4[1];
        acc[2] = bias4[2] + (float)g4[2];
        acc[3] = bias4[3] + (float)g4[3];
        #pragma unroll
        for (int kt = 0; kt < 8; ++kt) {
            h8_t bf = *(const h8_t*)(hbufT + ((nt * 8 + kt) << 9) + (lane << 3));
            acc = __builtin_amdgcn_mfma_f32_16x16x32_f16(Afr[kt], bf, acc, 0, 0, 0);
        }

        const int nl = nt * 16 + l15;
        gbuf[(mq + 0) * 34 + nl] = acc[0];
        gbuf[(mq + 1) * 34 + nl] = acc[1];
        gbuf[(mq + 2) * 34 + nl] = acc[2];
        gbuf[(mq + 3) * 34 + nl] = acc[3];
        __syncthreads();                  // gates ready

        // activation: all 256 threads, one h value each (row 8j+rl, batch n32)
        {
            float gi = gbuf[(0 * 8 + rl) * 34 + n32];
            float gf = gbuf[(1 * 8 + rl) * 34 + n32];
            float gg = gbuf[(2 * 8 + rl) * 34 + n32];
            float go = gbuf[(3 * 8 + rl) * 34 + n32];
            float si = 1.f / (1.f + expf(-gi));
            float sf = 1.f / (1.f + expf(-gf));
            float so = 1.f / (1.f + expf(-go));
            c = sf * c + si * tanhf(gg);
            float h = so * tanhf(c);
            hp[0] = h;
            float hn = __shfl_down(h, 32, 64);     // partner row rl+1
            if ((t & 32) == 0 && s < T_ - 1) {     // even rl publishes pair
                h2_t pk; pk[0] = (_Float16)h; pk[1] = (_Float16)hn;
                __hip_atomic_store(mailG + ((size_t)s * 128 + 4 * j + wv) * 32 + n32,
                                   __builtin_bit_cast(unsigned int, pk),
                                   __ATOMIC_RELAXED, __HIP_MEMORY_SCOPE_AGENT);
            }
        }
        gp += gstep;
        hp += hstep;
        // no 3rd barrier needed: next gather touches only hbufT (reads of
        // which finished before barrier 2), and next gbuf write happens
        // after next barrier 1.
    }
}

// ---------------------------------------------------------------------------
// Kernel C: feats[m, o] = concat(hf[m], hb[m]) . w_out[o, :] + b_out[o]
// ---------------------------------------------------------------------------
__global__ __launch_bounds__(256)
void feats_proj(const float* __restrict__ hf, const float* __restrict__ hb,
                const float* __restrict__ w_out, const float* __restrict__ b_out,
                float* __restrict__ feats)
{
    const int lane = threadIdx.x & 63;
    const int wv   = threadIdx.x >> 6;
    const int m    = blockIdx.x * 4 + wv;
    const int o    = lane & 15;
    const int qq   = lane >> 4;

    const float* hsrc = (qq < 2) ? (hf + (size_t)m * 256 + qq * 128)
                                 : (hb + (size_t)m * 256 + (qq - 2) * 128);
    const float4* h4 = (const float4*)hsrc;
    const float4* w4 = (const float4*)(w_out + o * 512 + qq * 128);

    float acc = 0.f;
    #pragma unroll
    for (int i = 0; i < 32; ++i) {
        float4 hv = h4[i], wvv = w4[i];
        acc = fmaf(hv.x, wvv.x, acc);
        acc = fmaf(hv.y, wvv.y, acc);
        acc = fmaf(hv.z, wvv.z, acc);
        acc = fmaf(hv.w, wvv.w, acc);
    }
    acc += __shfl_xor(acc, 16, 64);
    acc += __shfl_xor(acc, 32, 64);
    if (lane < 16) feats[(size_t)m * 16 + o] = acc + b_out[o];
}

// ---------------------------------------------------------------------------
// Kernel D: Viterbi + backtrace.
// ---------------------------------------------------------------------------
__global__ __launch_bounds__(64)
void viterbi(const float* __restrict__ feats, const float* __restrict__ trans,
             float* __restrict__ out)
{
    __shared__ unsigned char bp[T_][16];
    const int b    = blockIdx.x;
    const int lane = threadIdx.x;
    const int l15  = lane & 15;

    float tr[16];
    #pragma unroll
    for (int p = 0; p < 16; ++p)
        tr[p] = (lane < 16) ? trans[lane * 16 + p] : 0.f;

    float fv = (lane == START_) ? 0.f : NEG_;

    for (int t4 = 0; t4 < T_; t4 += 4) {
        float fblk = feats[((size_t)(t4 + (lane >> 4)) * 64 + b) * 16 + l15];
        #pragma unroll
        for (int tt = 0; tt < 4; ++tt) {
            const int t = t4 + tt;
            float best = -3.4e38f; int arg = 0;
            #pragma unroll
            for (int p = 0; p < 16; ++p) {
                float s = __shfl(fv, p, 64) + tr[p];
                if (s > best) { best = s; arg = p; }
            }
            float ft = __shfl(fblk, tt * 16 + l15, 64);
            if (lane < 16) {
                fv = best + ft;
                bp[t][lane] = (unsigned char)arg;
            }
        }
    }

    float term = fv + ((lane < 16) ? trans[STOP_ * 16 + lane] : 0.f);
    float v  = (lane < 16) ? term : -3.4e38f;
    int  idx = (lane < 16) ? lane : (1 << 20);
    #pragma unroll
    for (int off = 1; off < 64; off <<= 1) {
        float v2 = __shfl_xor(v, off, 64);
        int   i2 = __shfl_xor(idx, off, 64);
        if (v2 > v || (v2 == v && i2 < idx)) { v = v2; idx = i2; }
    }
    __syncthreads();
    if (lane == 0) {
        out[b] = v;
        int tag = idx;
        for (int t = T_ - 1; t >= 0; --t) {
            out[64 + (size_t)t * 64 + b] = (float)tag;
            tag = bp[t][tag];
        }
    }
}

// ---------------------------------------------------------------------------
extern "C" void kernel_launch(void* const* d_in, const int* in_sizes, int n_in,
                              void* d_out, int out_size, void* d_ws, size_t ws_size,
                              hipStream_t stream) {
    const int*   sentence = (const int*)d_in[0];
    const float* emb      = (const float*)d_in[1];
    const float* w_ih_f   = (const float*)d_in[2];
    const float* w_hh_f   = (const float*)d_in[3];
    const float* b_f      = (const float*)d_in[4];
    const float* w_ih_b   = (const float*)d_in[5];
    const float* w_hh_b   = (const float*)d_in[6];
    const float* b_b      = (const float*)d_in[7];
    const float* w_out    = (const float*)d_in[8];
    const float* b_out    = (const float*)d_in[9];
    const float* trans    = (const float*)d_in[10];
    float* out = (float*)d_out;

    // workspace: gin_f|gin_b (fp16 64MB ea) | hf|hb (fp32 32MB ea) |
    //            feats (2MB) | wih16 (1MB) | wreg3 (1MB) | mail (32MB)
    _Float16* gin_f = (_Float16*)d_ws;
    _Float16* gin_b = gin_f + (size_t)T_ * B_ * G_;
    float* hf    = (float*)(gin_b + (size_t)T_ * B_ * G_);
    float* hb    = hf + (size_t)T_ * B_ * H_;
    float* feats = hb + (size_t)T_ * B_ * H_;
    _Float16* wih16 = (_Float16*)(feats + (size_t)T_ * B_ * K_);
    _Float16* wreg3 = wih16 + 524288;
    unsigned int* mail = (unsigned int*)(wreg3 + 524288);

    prep_weights<<<288, 256, 0, stream>>>(w_hh_f, w_hh_b, w_ih_f, w_ih_b,
                                          wreg3, wih16);
    gates_mfma<<<dim3(512, 2), 256, 0, stream>>>(sentence, emb, wih16,
                                                 gin_f, gin_b);
    hipMemsetAsync(mail, 0xFF, (size_t)33554432, stream);  // prime sentinels
    lstm_gemm<<<128, 256, 0, stream>>>(gin_f, gin_b, wreg3, b_f, b_b,
                                       hf, hb, mail);
    feats_proj<<<8192, 256, 0, stream>>>(hf, hb, w_out, b_out, feats);
    viterbi<<<64, 64, 0, stream>>>(feats, trans, out);
}

// Round 4
// 2392.557 us; speedup vs baseline: 1.3380x; 1.3380x over previous
//
#include <hip/hip_runtime.h>
#include <math.h>

typedef _Float16 h2_t  __attribute__((ext_vector_type(2)));
typedef _Float16 h4_t  __attribute__((ext_vector_type(4)));
typedef _Float16 h8_t  __attribute__((ext_vector_type(8)));
typedef float    f4_t  __attribute__((ext_vector_type(4)));

#define T_ 512
#define B_ 64
#define E_ 256
#define H_ 256
#define G_ 1024   // 4*H
#define K_ 16
#define NEG_ (-10000.0f)
#define START_ 14
#define STOP_ 15

// ---------------------------------------------------------------------------
// Prep: pack all weights to fp16 in the layouts the hot kernels want.
//  wregA: MFMA A-fragments for the pairwise recurrent GEMM.
//         h8 idx = (((dir*2+half)*32 + mt)*8 + kt)*64 + lane
//         lane holds A[m = mt*16 + (lane&15)][k = kt*32 + (lane>>4)*8 + e]
//         local row m -> gate γ=m>>7, r=m&127, global row γ*256+half*128+r
//         k-order: kt<4 -> OWN half h (half*128 + kt*32+..),
//                  kt>=4 -> PARTNER half ((1-half)*128 + (kt-4)*32+..) -> 1 MB
//  wih16: [dir][row 0..1023][k 0..255] fp16 copy of w_ih               -> 1 MB
// ---------------------------------------------------------------------------
__global__ __launch_bounds__(256)
void prep_weights(const float* __restrict__ w_hh_f,
                  const float* __restrict__ w_hh_b,
                  const float* __restrict__ w_ih_f,
                  const float* __restrict__ w_ih_b,
                  _Float16* __restrict__ wregA,
                  _Float16* __restrict__ wih16)
{
    const int blk = blockIdx.x, tid = threadIdx.x;
    if (blk < 256) {                      // wregA: 65536 h8 entries
        int idx  = blk * 256 + tid;
        int lane = idx & 63;
        int kt   = (idx >> 6) & 7;
        int mt   = (idx >> 9) & 31;
        int half = (idx >> 14) & 1;
        int dir  = idx >> 15;
        int m    = mt * 16 + (lane & 15);
        int grow = (m >> 7) * 256 + half * 128 + (m & 127);
        int koff = (lane >> 4) * 8;
        int hbase = (kt < 4) ? (half * 128 + kt * 32 + koff)
                             : ((1 - half) * 128 + (kt - 4) * 32 + koff);
        const float* src = (dir ? w_hh_b : w_hh_f) + (size_t)grow * 256 + hbase;
        h8_t o;
        #pragma unroll
        for (int e = 0; e < 8; ++e) o[e] = (_Float16)src[e];
        ((h8_t*)wregA)[idx] = o;
    } else {                              // wih16: 65536 x h8
        int idx = (blk - 256) * 256 + tid;
        int dir = idx / 32768, rem = idx % 32768;
        const float* src = (dir ? w_ih_b : w_ih_f) + (size_t)rem * 8;
        _Float16* dst = wih16 + (size_t)idx * 8;
        #pragma unroll
        for (int i = 0; i < 8; ++i) dst[i] = (_Float16)src[i];
    }
}

// ---------------------------------------------------------------------------
// Kernel A: input-gate GEMM via f16 MFMA 16x16x32. Bias is PRE-ADDED here
// (fp32, before the fp16 store) so the recurrent kernel needs no bias.
// ---------------------------------------------------------------------------
__global__ __launch_bounds__(256)
void gates_mfma(const int* __restrict__ sentence,
                const float* __restrict__ emb,
                const _Float16* __restrict__ wih16,
                const float* __restrict__ b_f,
                const float* __restrict__ b_b,
                _Float16* __restrict__ gin_f,
                _Float16* __restrict__ gin_b)
{
    __shared__ _Float16 As[64 * 264];
    __shared__ _Float16 Bs[256 * 40];
    __shared__ int sidx[64];

    const int bm  = blockIdx.x;           // t
    const int dir = blockIdx.y;
    const int tid = threadIdx.x;

    const _Float16* __restrict__ wih = wih16 + (size_t)dir * 262144;
    const float*    __restrict__ bsd = dir ? b_b : b_f;
    _Float16* __restrict__ gout      = dir ? gin_b : gin_f;

    if (tid < 64) sidx[tid] = sentence[tid * T_ + bm];
    __syncthreads();

    {   // stage A (emb gather, fp32 -> fp16)
        const int r = tid & 63, kq = tid >> 6;
        const float4* src = (const float4*)(emb + (size_t)sidx[r] * 256 + kq * 64);
        _Float16* dst = As + r * 264 + kq * 64;
        #pragma unroll
        for (int c = 0; c < 8; ++c) {
            float4 v0 = src[2 * c], v1 = src[2 * c + 1];
            h8_t o;
            o[0] = (_Float16)v0.x; o[1] = (_Float16)v0.y;
            o[2] = (_Float16)v0.z; o[3] = (_Float16)v0.w;
            o[4] = (_Float16)v1.x; o[5] = (_Float16)v1.y;
            o[6] = (_Float16)v1.z; o[7] = (_Float16)v1.w;
            *(h8_t*)(dst + c * 8) = o;
        }
    }

    const int wave = tid >> 6, lane = tid & 63;
    const int l15 = lane & 15, quad = lane >> 4;

    for (int pass = 0; pass < 4; ++pass) {
        const int n0 = pass * 256;
        f4_t acc[16];
        #pragma unroll
        for (int nt = 0; nt < 16; ++nt) acc[nt] = (f4_t){0.f, 0.f, 0.f, 0.f};

        for (int kc = 0; kc < 8; ++kc) {
            __syncthreads();
            {
                const h8_t* bsrc = (const h8_t*)(wih + (size_t)(n0 + tid) * 256 + kc * 32);
                #pragma unroll
                for (int c = 0; c < 4; ++c)
                    *(h8_t*)(Bs + tid * 40 + c * 8) = bsrc[c];
            }
            __syncthreads();
            h8_t a = *(const h8_t*)(As + (wave * 16 + l15) * 264 + kc * 32 + quad * 8);
            #pragma unroll
            for (int nt = 0; nt < 16; ++nt) {
                h8_t b = *(const h8_t*)(Bs + (nt * 16 + l15) * 40 + quad * 8);
                acc[nt] = __builtin_amdgcn_mfma_f32_16x16x32_f16(a, b, acc[nt], 0, 0, 0);
            }
        }

        const size_t mbase = (size_t)bm * 64 + wave * 16 + quad * 4;
        #pragma unroll
        for (int nt = 0; nt < 16; ++nt) {
            const int col = n0 + nt * 16 + l15;
            const float bias = bsd[col];
            #pragma unroll
            for (int r = 0; r < 4; ++r)
                gout[(mbase + r) * 1024 + col] = (_Float16)(acc[nt][r] + bias);
        }
    }
}

// ---------------------------------------------------------------------------
// Kernel B: pairwise MFMA LSTM.
// 16 blocks = (dir, half-of-hidden, batch-quarter), 1024 threads = 16 waves
// (1 block/CU, VGPR capped at 128 by flat_work_group_size=1024).
// Per step: G[512,16] = W[512,256] . h[256,16] as 256 x mfma 16x16x32_f16
// (wave w owns m-tiles {2w,2w+1}; A-frags = 16 h8 = 64 VGPRs, loaded once —
// MFMA reads them natively from the unified VGPR/AGPR file, so there is no
// per-use copy regardless of allocator placement).
// K-order: own-half h first (kt 0..3) -> those MFMAs run while the partner
// mailbox uint is in flight; partner half (kt 4..7) after one barrier.
// Exchange is PAIRWISE (round 3's 32-way gather was the disaster): 4 KB =
// 1024 uints per step, fragment-linear in the POLLER's B layout so poll
// loads are fully coalesced (1 uint/thread); publisher eats the scatter.
// Sentinel 0xFFFFFFFF = fp16 NaN pair (|h|<1 -> unreachable), relaxed
// agent-scope atomics. 16 blocks trivially co-resident -> no deadlock.
// ---------------------------------------------------------------------------
__global__ __launch_bounds__(1024)
void lstm_mfma(const _Float16* __restrict__ gin_f,
               const _Float16* __restrict__ gin_b,
               const _Float16* __restrict__ wregA,
               float* __restrict__ hf, float* __restrict__ hb,
               unsigned int* __restrict__ mail)
{
    __shared__ _Float16 Bs[4096];      // 8 KB: [kt 0..7][lane][e], own=kt<4
    __shared__ float    gbuf[9216];    // 36 KB: [m 0..511][n 0..15], stride 18

    const int bid  = blockIdx.x;       // (dir*2 + half)*4 + bq
    const int dir  = bid >> 3;
    const int half = (bid >> 2) & 1;
    const int bq   = bid & 3;
    const int t    = threadIdx.x;
    const int w    = t >> 6, lane = t & 63;
    const int l15  = lane & 15, quad = lane >> 4;

    const _Float16* __restrict__ gin  = dir ? gin_b : gin_f;
    float*          __restrict__ hout = dir ? hb : hf;

    // A-fragments: wave w owns m-tiles 2w (acc0) and 2w+1 (acc1)
    const h8_t* ap = (const h8_t*)wregA +
                     (((size_t)(dir * 2 + half) * 32 + 2 * w) * 8) * 64 + lane;
    h8_t A0[8], A1[8];
    #pragma unroll
    for (int kt = 0; kt < 8; ++kt) A0[kt] = ap[kt * 64];
    #pragma unroll
    for (int kt = 0; kt < 8; ++kt) A1[kt] = ap[512 + kt * 64];

    // gin addressing for the two acc row-quads (bias pre-added in gates_mfma)
    const int m0  = w * 32 + quad * 4;         // rows m0..m0+3 (acc0)
    const int gr0 = (m0 >> 7) * 256 + half * 128 + (m0 & 127);
    const int m1  = m0 + 16;                   // rows m1..m1+3 (acc1)
    const int gr1 = (m1 >> 7) * 256 + half * 128 + (m1 & 127);
    const int bcol = bq * 16 + l15;
    const int s0   = dir ? (T_ - 1) : 0;
    const _Float16* gp = gin + ((size_t)s0 * 64 + bcol) * 1024;
    const long gstep = (dir ? -1L : 1L) * 65536;

    // activation identity: thread t -> batch col nact, h rows hr0=2*(t>>4), +1
    const int nact = t & 15;
    const int hr0  = (t >> 4) * 2;
    const int ktl  = hr0 >> 5;
    const int lhi  = (hr0 >> 3) & 3;
    const int ep   = (hr0 >> 1) & 3;
    const int uidx = ktl * 256 + (lhi * 16 + nact) * 4 + ep;  // own-Bs & mail idx
    unsigned int* mailPub =
        mail + ((size_t)((dir * 2 + half) * 4 + bq)) * T_ * 1024 + uidx;
    const unsigned int* mailPoll =
        mail + ((size_t)((dir * 2 + (1 - half)) * 4 + bq)) * T_ * 1024 + t;
    float* hp = hout + ((size_t)s0 * 64 + bq * 16 + nact) * 256 + half * 128 + hr0;
    const long hstep = (dir ? -1L : 1L) * (64 * 256);

    unsigned int* BsU = (unsigned int*)Bs;
    BsU[t] = 0u; BsU[t + 1024] = 0u;          // h(-1) = 0 (own + partner)
    float c0 = 0.f, c1 = 0.f;
    __syncthreads();

    h4_t gc0 = *(const h4_t*)(gp + gr0);
    h4_t gc1 = *(const h4_t*)(gp + gr1);

    for (int s = 0; s < T_; ++s) {
        const _Float16* gpn = gp + gstep;
        h4_t gn0 = *(const h4_t*)(gpn + gr0);  // prefetch (safe overread @ end)
        h4_t gn1 = *(const h4_t*)(gpn + gr1);

        // non-blocking partner poll issue (checked after phase-1 MFMAs)
        unsigned int u = 0xFFFFFFFFu;
        if (s > 0)
            u = __hip_atomic_load(mailPoll + (size_t)(s - 1) * 1024,
                                  __ATOMIC_RELAXED, __HIP_MEMORY_SCOPE_AGENT);

        f4_t acc0, acc1;
        #pragma unroll
        for (int r = 0; r < 4; ++r) { acc0[r] = (float)gc0[r]; acc1[r] = (float)gc1[r]; }

        #pragma unroll
        for (int kt = 0; kt < 4; ++kt) {       // phase 1: own-half k
            h8_t bf = *(const h8_t*)(Bs + kt * 512 + lane * 8);
            acc0 = __builtin_amdgcn_mfma_f32_16x16x32_f16(A0[kt], bf, acc0, 0, 0, 0);
            acc1 = __builtin_amdgcn_mfma_f32_16x16x32_f16(A1[kt], bf, acc1, 0, 0, 0);
        }

        if (s > 0) {
            int guard = 0;
            while (u == 0xFFFFFFFFu && ++guard < (1 << 20))
                u = __hip_atomic_load(mailPoll + (size_t)(s - 1) * 1024,
                                      __ATOMIC_RELAXED, __HIP_MEMORY_SCOPE_AGENT);
            BsU[1024 + t] = u;                 // partner region (s=0 stays zero)
        }
        __syncthreads();                       // partner h(s-1) staged

        #pragma unroll
        for (int kt = 4; kt < 8; ++kt) {       // phase 2: partner-half k
            h8_t bf = *(const h8_t*)(Bs + kt * 512 + lane * 8);
            acc0 = __builtin_amdgcn_mfma_f32_16x16x32_f16(A0[kt], bf, acc0, 0, 0, 0);
            acc1 = __builtin_amdgcn_mfma_f32_16x16x32_f16(A1[kt], bf, acc1, 0, 0, 0);
        }

        #pragma unroll
        for (int r = 0; r < 4; ++r) gbuf[(m0 + r) * 18 + l15] = acc0[r];
        #pragma unroll
        for (int r = 0; r < 4; ++r) gbuf[(m1 + r) * 18 + l15] = acc1[r];
        __syncthreads();                       // gates ready

        {   // activation: rows hr0, hr0+1 for batch col nact
            float i0 = gbuf[(      hr0) * 18 + nact];
            float f0 = gbuf[(128 + hr0) * 18 + nact];
            float g0 = gbuf[(256 + hr0) * 18 + nact];
            float o0 = gbuf[(384 + hr0) * 18 + nact];
            float i1 = gbuf[(      hr0 + 1) * 18 + nact];
            float f1 = gbuf[(128 + hr0 + 1) * 18 + nact];
            float g1 = gbuf[(256 + hr0 + 1) * 18 + nact];
            float o1 = gbuf[(384 + hr0 + 1) * 18 + nact];
            float si0 = 1.f / (1.f + expf(-i0)), sf0 = 1.f / (1.f + expf(-f0));
            float so0 = 1.f / (1.f + expf(-o0));
            float si1 = 1.f / (1.f + expf(-i1)), sf1 = 1.f / (1.f + expf(-f1));
            float so1 = 1.f / (1.f + expf(-o1));
            c0 = sf0 * c0 + si0 * tanhf(g0);
            c1 = sf1 * c1 + si1 * tanhf(g1);
            float h0v = so0 * tanhf(c0);
            float h1v = so1 * tanhf(c1);

            h2_t pk; pk[0] = (_Float16)h0v; pk[1] = (_Float16)h1v;
            unsigned int up = __builtin_bit_cast(unsigned int, pk);
            if (s < T_ - 1)                    // publish FIRST (critical path)
                __hip_atomic_store(mailPub + (size_t)s * 1024, up,
                                   __ATOMIC_RELAXED, __HIP_MEMORY_SCOPE_AGENT);
            BsU[uidx] = up;                    // own region for next phase 1
            *(float2*)hp = make_float2(h0v, h1v);
        }
        gc0 = gn0; gc1 = gn1;
        gp = gpn; hp += hstep;
        __syncthreads();                       // own h(s) visible block-wide
    }
}

// ---------------------------------------------------------------------------
// Kernel C: feats[m, o] = concat(hf[m], hb[m]) . w_out[o, :] + b_out[o]
// ---------------------------------------------------------------------------
__global__ __launch_bounds__(256)
void feats_proj(const float* __restrict__ hf, const float* __restrict__ hb,
                const float* __restrict__ w_out, const float* __restrict__ b_out,
                float* __restrict__ feats)
{
    const int lane = threadIdx.x & 63;
    const int wv   = threadIdx.x >> 6;
    const int m    = blockIdx.x * 4 + wv;
    const int o    = lane & 15;
    const int qq   = lane >> 4;

    const float* hsrc = (qq < 2) ? (hf + (size_t)m * 256 + qq * 128)
                                 : (hb + (size_t)m * 256 + (qq - 2) * 128);
    const float4* h4 = (const float4*)hsrc;
    const float4* w4 = (const float4*)(w_out + o * 512 + qq * 128);

    float acc = 0.f;
    #pragma unroll
    for (int i = 0; i < 32; ++i) {
        float4 hv = h4[i], wvv = w4[i];
        acc = fmaf(hv.x, wvv.x, acc);
        acc = fmaf(hv.y, wvv.y, acc);
        acc = fmaf(hv.z, wvv.z, acc);
        acc = fmaf(hv.w, wvv.w, acc);
    }
    acc += __shfl_xor(acc, 16, 64);
    acc += __shfl_xor(acc, 32, 64);
    if (lane < 16) feats[(size_t)m * 16 + o] = acc + b_out[o];
}

// ---------------------------------------------------------------------------
// Kernel D: Viterbi + backtrace.
// ---------------------------------------------------------------------------
__global__ __launch_bounds__(64)
void viterbi(const float* __restrict__ feats, const float* __restrict__ trans,
             float* __restrict__ out)
{
    __shared__ unsigned char bp[T_][16];
    const int b    = blockIdx.x;
    const int lane = threadIdx.x;
    const int l15  = lane & 15;

    float tr[16];
    #pragma unroll
    for (int p = 0; p < 16; ++p)
        tr[p] = (lane < 16) ? trans[lane * 16 + p] : 0.f;

    float fv = (lane == START_) ? 0.f : NEG_;

    for (int t4 = 0; t4 < T_; t4 += 4) {
        float fblk = feats[((size_t)(t4 + (lane >> 4)) * 64 + b) * 16 + l15];
        #pragma unroll
        for (int tt = 0; tt < 4; ++tt) {
            const int t = t4 + tt;
            float best = -3.4e38f; int arg = 0;
            #pragma unroll
            for (int p = 0; p < 16; ++p) {
                float s = __shfl(fv, p, 64) + tr[p];
                if (s > best) { best = s; arg = p; }
            }
            float ft = __shfl(fblk, tt * 16 + l15, 64);
            if (lane < 16) {
                fv = best + ft;
                bp[t][lane] = (unsigned char)arg;
            }
        }
    }

    float term = fv + ((lane < 16) ? trans[STOP_ * 16 + lane] : 0.f);
    float v  = (lane < 16) ? term : -3.4e38f;
    int  idx = (lane < 16) ? lane : (1 << 20);
    #pragma unroll
    for (int off = 1; off < 64; off <<= 1) {
        float v2 = __shfl_xor(v, off, 64);
        int   i2 = __shfl_xor(idx, off, 64);
        if (v2 > v || (v2 == v && i2 < idx)) { v = v2; idx = i2; }
    }
    __syncthreads();
    if (lane == 0) {
        out[b] = v;
        int tag = idx;
        for (int t = T_ - 1; t >= 0; --t) {
            out[64 + (size_t)t * 64 + b] = (float)tag;
            tag = bp[t][tag];
        }
    }
}

// ---------------------------------------------------------------------------
extern "C" void kernel_launch(void* const* d_in, const int* in_sizes, int n_in,
                              void* d_out, int out_size, void* d_ws, size_t ws_size,
                              hipStream_t stream) {
    const int*   sentence = (const int*)d_in[0];
    const float* emb      = (const float*)d_in[1];
    const float* w_ih_f   = (const float*)d_in[2];
    const float* w_hh_f   = (const float*)d_in[3];
    const float* b_f      = (const float*)d_in[4];
    const float* w_ih_b   = (const float*)d_in[5];
    const float* w_hh_b   = (const float*)d_in[6];
    const float* b_b      = (const float*)d_in[7];
    const float* w_out    = (const float*)d_in[8];
    const float* b_out    = (const float*)d_in[9];
    const float* trans    = (const float*)d_in[10];
    float* out = (float*)d_out;

    // workspace: gin_f|gin_b (fp16 64MB ea) | hf|hb (fp32 32MB ea) |
    //            feats (2MB) | wih16 (1MB) | wregA (1MB) | mail (32MB)
    _Float16* gin_f = (_Float16*)d_ws;
    _Float16* gin_b = gin_f + (size_t)T_ * B_ * G_;
    float* hf    = (float*)(gin_b + (size_t)T_ * B_ * G_);
    float* hb    = hf + (size_t)T_ * B_ * H_;
    float* feats = hb + (size_t)T_ * B_ * H_;
    _Float16* wih16 = (_Float16*)(feats + (size_t)T_ * B_ * K_);
    _Float16* wregA = wih16 + 524288;
    unsigned int* mail = (unsigned int*)(wregA + 524288);

    prep_weights<<<512, 256, 0, stream>>>(w_hh_f, w_hh_b, w_ih_f, w_ih_b,
                                          wregA, wih16);
    gates_mfma<<<dim3(512, 2), 256, 0, stream>>>(sentence, emb, wih16,
                                                 b_f, b_b, gin_f, gin_b);
    hipMemsetAsync(mail, 0xFF, (size_t)33554432, stream);  // prime sentinels
    lstm_mfma<<<16, 1024, 0, stream>>>(gin_f, gin_b, wregA, hf, hb, mail);
    feats_proj<<<8192, 256, 0, stream>>>(hf, hb, w_out, b_out, feats);
    viterbi<<<64, 64, 0, stream>>>(feats, trans, out);
}

// Round 5
// 2083.410 us; speedup vs baseline: 1.5365x; 1.1484x over previous
//
#include <hip/hip_runtime.h>
#include <math.h>

typedef _Float16 h2_t  __attribute__((ext_vector_type(2)));
typedef _Float16 h4_t  __attribute__((ext_vector_type(4)));
typedef _Float16 h8_t  __attribute__((ext_vector_type(8)));
typedef float    f4_t  __attribute__((ext_vector_type(4)));
typedef unsigned int u4_t __attribute__((ext_vector_type(4)));

#define T_ 512
#define B_ 64
#define E_ 256
#define H_ 256
#define G_ 1024   // 4*H
#define K_ 16
#define NEG_ (-10000.0f)
#define START_ 14
#define STOP_ 15

static __device__ __forceinline__ float fsig(float x) {
    return __builtin_amdgcn_rcpf(1.f + __builtin_amdgcn_exp2f(-1.4426950408889634f * x));
}
static __device__ __forceinline__ float ftanh(float x) {
    return 1.f - 2.f * __builtin_amdgcn_rcpf(1.f + __builtin_amdgcn_exp2f(2.8853900817779268f * x));
}

// ---------------------------------------------------------------------------
// Prep: pack weights.
//  wregB: A-fragments for the 32-block recurrent GEMM.
//         h8 idx = (((dir*4+hq)*16 + mt)*8 + kt)*64 + lane
//         lane holds A[m_local = mt*16+(lane&15)][k = kt*32+(lane>>4)*8+e]
//         m_local = u*4+γ (gates interleaved!) -> global row γ*256+hq*64+u
//                                                                    -> 1 MB
//  wih16: [dir][row 0..1023][k 0..255] fp16 copy of w_ih            -> 1 MB
// ---------------------------------------------------------------------------
__global__ __launch_bounds__(256)
void prep_weights(const float* __restrict__ w_hh_f,
                  const float* __restrict__ w_hh_b,
                  const float* __restrict__ w_ih_f,
                  const float* __restrict__ w_ih_b,
                  _Float16* __restrict__ wregB,
                  _Float16* __restrict__ wih16)
{
    const int blk = blockIdx.x, tid = threadIdx.x;
    if (blk < 256) {                      // wregB: 65536 h8 entries
        int e    = blk * 256 + tid;
        int lane = e & 63;
        int kt   = (e >> 6) & 7;
        int mt   = (e >> 9) & 15;
        int hq   = (e >> 13) & 3;
        int dir  = e >> 15;
        int ml   = mt * 16 + (lane & 15);
        int u    = ml >> 2, g = ml & 3;
        int row  = g * 256 + hq * 64 + u;
        int k    = kt * 32 + (lane >> 4) * 8;
        const float* src = (dir ? w_hh_b : w_hh_f) + (size_t)row * 256 + k;
        h8_t o;
        #pragma unroll
        for (int i = 0; i < 8; ++i) o[i] = (_Float16)src[i];
        ((h8_t*)wregB)[e] = o;
    } else {                              // wih16: 65536 x h8
        int idx = (blk - 256) * 256 + tid;
        int dir = idx / 32768, rem = idx % 32768;
        const float* src = (dir ? w_ih_b : w_ih_f) + (size_t)rem * 8;
        _Float16* dst = wih16 + (size_t)idx * 8;
        #pragma unroll
        for (int i = 0; i < 8; ++i) dst[i] = (_Float16)src[i];
    }
}

// ---------------------------------------------------------------------------
// Kernel A: input-gate GEMM via f16 MFMA 16x16x32. Bias pre-added.
// Output layout now TRANSPOSED for the recurrent kernel:
//   gin2[dir][t][gcol 0..1023][b 0..63]  (h4-contiguous stores in b).
// ---------------------------------------------------------------------------
__global__ __launch_bounds__(256)
void gates_mfma(const int* __restrict__ sentence,
                const float* __restrict__ emb,
                const _Float16* __restrict__ wih16,
                const float* __restrict__ b_f,
                const float* __restrict__ b_b,
                _Float16* __restrict__ gin_f,
                _Float16* __restrict__ gin_b)
{
    __shared__ _Float16 As[64 * 264];
    __shared__ _Float16 Bs[256 * 40];
    __shared__ int sidx[64];

    const int bm  = blockIdx.x;           // t
    const int dir = blockIdx.y;
    const int tid = threadIdx.x;

    const _Float16* __restrict__ wih = wih16 + (size_t)dir * 262144;
    const float*    __restrict__ bsd = dir ? b_b : b_f;
    _Float16* __restrict__ gout      = dir ? gin_b : gin_f;

    if (tid < 64) sidx[tid] = sentence[tid * T_ + bm];
    __syncthreads();

    {   // stage A (emb gather, fp32 -> fp16)
        const int r = tid & 63, kq = tid >> 6;
        const float4* src = (const float4*)(emb + (size_t)sidx[r] * 256 + kq * 64);
        _Float16* dst = As + r * 264 + kq * 64;
        #pragma unroll
        for (int c = 0; c < 8; ++c) {
            float4 v0 = src[2 * c], v1 = src[2 * c + 1];
            h8_t o;
            o[0] = (_Float16)v0.x; o[1] = (_Float16)v0.y;
            o[2] = (_Float16)v0.z; o[3] = (_Float16)v0.w;
            o[4] = (_Float16)v1.x; o[5] = (_Float16)v1.y;
            o[6] = (_Float16)v1.z; o[7] = (_Float16)v1.w;
            *(h8_t*)(dst + c * 8) = o;
        }
    }

    const int wave = tid >> 6, lane = tid & 63;
    const int l15 = lane & 15, quad = lane >> 4;

    for (int pass = 0; pass < 4; ++pass) {
        const int n0 = pass * 256;
        f4_t acc[16];
        #pragma unroll
        for (int nt = 0; nt < 16; ++nt) acc[nt] = (f4_t){0.f, 0.f, 0.f, 0.f};

        for (int kc = 0; kc < 8; ++kc) {
            __syncthreads();
            {
                const h8_t* bsrc = (const h8_t*)(wih + (size_t)(n0 + tid) * 256 + kc * 32);
                #pragma unroll
                for (int c = 0; c < 4; ++c)
                    *(h8_t*)(Bs + tid * 40 + c * 8) = bsrc[c];
            }
            __syncthreads();
            h8_t a = *(const h8_t*)(As + (wave * 16 + l15) * 264 + kc * 32 + quad * 8);
            #pragma unroll
            for (int nt = 0; nt < 16; ++nt) {
                h8_t b = *(const h8_t*)(Bs + (nt * 16 + l15) * 40 + quad * 8);
                acc[nt] = __builtin_amdgcn_mfma_f32_16x16x32_f16(a, b, acc[nt], 0, 0, 0);
            }
        }

        const size_t tbase = (size_t)bm * 65536;
        const int brow = wave * 16 + quad * 4;         // batch base (4 consec)
        #pragma unroll
        for (int nt = 0; nt < 16; ++nt) {
            const int col = n0 + nt * 16 + l15;        // gate col 0..1023
            const float bias = bsd[col];
            h4_t o4;
            #pragma unroll
            for (int r = 0; r < 4; ++r) o4[r] = (_Float16)(acc[nt][r] + bias);
            *(h4_t*)(gout + tbase + (size_t)col * 64 + brow) = o4;
        }
    }
}

// ---------------------------------------------------------------------------
// Kernel B: 32-block MFMA LSTM with asm-pinned A-fragments.
// blocks: id = hq*8 + dir*4 + bq  (4 partner blocks of a (dir,bq) group land
// on the same XCD under round-robin — perf-only assumption).
// Per block: M=256 local gate rows (64 units x 4 gates INTERLEAVED m=u*4+γ),
// N=16 batch, K=256 per step = 128 mfma_f32_16x16x32_f16 over 8 waves
// (wave w owns m-tiles {w, w+8}). Gate interleave => each lane's f4 acc =
// (i,f,g,o) of ONE unit => activation fully in-register, no gbuf, ONE
// barrier/step.
// A-fragments (16 h8 = 64 VGPR) loaded by VOLATILE INLINE ASM global_load —
// un-rematerializable, so the allocator MUST keep them resident (rounds 1-4
// all lost this fight with plain loads; R4's VGPR=60 => 256KB/step L2 reload
// was the 8680cyc/step). waves_per_eu(2,2): budget 256, need ~110.
// Exchange: per (dir,bq) group, per step, a 2048-uint mail region laid out
// exactly as the B-fragment image. Each block publishes its 512 uints
// (sentinel 0xFFFFFFFF = fp16 NaN pair, |h|<1 unreachable; relaxed
// agent-scope atomics); every thread polls 4 coalesced uints (incl. own
// region) straight into the double-buffered Bs. 32 blocks co-resident =>
// spin cannot deadlock.
// ---------------------------------------------------------------------------
__global__ __attribute__((amdgpu_flat_work_group_size(512, 512),
                          amdgpu_waves_per_eu(2, 2)))
void lstm_ring(const _Float16* __restrict__ gin_f,
               const _Float16* __restrict__ gin_b,
               const _Float16* __restrict__ wregB,
               float* __restrict__ hf, float* __restrict__ hb,
               unsigned int* __restrict__ mail)
{
    __shared__ unsigned int BsU[4096];    // 16 KB: 2 x 2048-uint B images

    const int id  = blockIdx.x;
    const int hq  = id >> 3;
    const int dir = (id >> 2) & 1;
    const int bq  = id & 3;
    const int t   = threadIdx.x;          // 0..511
    const int w   = t >> 6, lane = t & 63;
    const int n   = lane & 15, q = lane >> 4;

    const _Float16* __restrict__ gin  = dir ? gin_b : gin_f;
    float*          __restrict__ hout = dir ? hb : hf;

    // ---- A-fragments: 16 x h8 = 64 VGPRs, asm-forced residency ----
    const h8_t* wp = (const h8_t*)wregB +
                     ((size_t)((dir * 4 + hq) * 16 + w) * 8) * 64 + lane;
    u4_t Au[16];
    #pragma unroll
    for (int kt = 0; kt < 8; ++kt) {
        const void* p0 = (const void*)(wp + kt * 64);
        const void* p1 = (const void*)(wp + 4096 + kt * 64);
        asm volatile("global_load_dwordx4 %0, %1, off\n\ts_waitcnt vmcnt(0)"
                     : "=v"(Au[kt]) : "v"(p0));
        asm volatile("global_load_dwordx4 %0, %1, off\n\ts_waitcnt vmcnt(0)"
                     : "=v"(Au[8 + kt]) : "v"(p1));
    }

    // ---- identities ----
    const int u0  = w * 4 + q;            // local unit (mt = w)
    const int k0  = hq * 64 + u0;         // global k / h index (this dir)
    const int k1  = k0 + 32;              // mt = w+8
    const int b   = bq * 16 + n;

    const int s0  = dir ? (T_ - 1) : 0;
    // gin2 idx = t*65536 + gcol*64 + b ; gcol = γ*256 + k
    const _Float16* gp = gin + (size_t)s0 * 65536 + (size_t)k0 * 64 + b;
    const long gstep = (dir ? -1L : 1L) * 65536;

    float* hp = hout + ((size_t)s0 * 64 + b) * 256;
    const long hstep = (dir ? -1L : 1L) * (64 * 256);

    unsigned int* mailGrp = mail + (size_t)(dir * 4 + bq) * (512 * 2048);
    const bool pub = ((q & 1) == 0);
    const int pu0 = ((k0 >> 5) << 8) + (((k0 >> 3) & 3) << 6) + (n << 2) + ((k0 >> 1) & 3);
    const int pu1 = pu0 + 256;            // k1 = k0+32 -> next kt region

    // ---- init: h(-1) = 0 in buffer 0 ----
    BsU[t] = 0u; BsU[t + 512] = 0u; BsU[t + 1024] = 0u; BsU[t + 1536] = 0u;
    float c0 = 0.f, c1 = 0.f;
    int p = 0;
    __syncthreads();

    // current-step gin (8 scalars: 2 units x 4 gates)
    _Float16 ga0 = gp[0],     ga1 = gp[16384], ga2 = gp[32768], ga3 = gp[49152];
    _Float16 gb0 = gp[2048],  gb1 = gp[18432], gb2 = gp[34816], gb3 = gp[51200];

    for (int s = 0; s < T_; ++s) {
        const _Float16* gpn = gp + gstep;      // prefetch (safe overread)
        _Float16 na0 = gpn[0],    na1 = gpn[16384], na2 = gpn[32768], na3 = gpn[49152];
        _Float16 nb0 = gpn[2048], nb1 = gpn[18432], nb2 = gpn[34816], nb3 = gpn[51200];

        f4_t a0, a1;
        a0[0] = (float)ga0; a0[1] = (float)ga1; a0[2] = (float)ga2; a0[3] = (float)ga3;
        a1[0] = (float)gb0; a1[1] = (float)gb1; a1[2] = (float)gb2; a1[3] = (float)gb3;

        const h8_t* Bf = (const h8_t*)(BsU + p * 2048);
        #pragma unroll
        for (int kt = 0; kt < 8; ++kt) {
            h8_t bf = Bf[kt * 64 + lane];
            a0 = __builtin_amdgcn_mfma_f32_16x16x32_f16(
                     __builtin_bit_cast(h8_t, Au[kt]), bf, a0, 0, 0, 0);
            a1 = __builtin_amdgcn_mfma_f32_16x16x32_f16(
                     __builtin_bit_cast(h8_t, Au[8 + kt]), bf, a1, 0, 0, 0);
        }

        // activation (all in-register; acc = i,f,g,o of one unit)
        c0 = fsig(a0[1]) * c0 + fsig(a0[0]) * ftanh(a0[2]);
        float h0 = fsig(a0[3]) * ftanh(c0);
        c1 = fsig(a1[1]) * c1 + fsig(a1[0]) * ftanh(a1[2]);
        float h1 = fsig(a1[3]) * ftanh(c1);

        hp[k0] = h0;
        hp[k1] = h1;

        if (s < T_ - 1) {
            float h0n = __shfl_down(h0, 16, 64);   // unit u0+1 (quad q+1)
            float h1n = __shfl_down(h1, 16, 64);
            unsigned int* ms = mailGrp + (size_t)s * 2048;
            if (pub) {
                h2_t pk0; pk0[0] = (_Float16)h0; pk0[1] = (_Float16)h0n;
                h2_t pk1; pk1[0] = (_Float16)h1; pk1[1] = (_Float16)h1n;
                __hip_atomic_store(ms + pu0, __builtin_bit_cast(unsigned int, pk0),
                                   __ATOMIC_RELAXED, __HIP_MEMORY_SCOPE_AGENT);
                __hip_atomic_store(ms + pu1, __builtin_bit_cast(unsigned int, pk1),
                                   __ATOMIC_RELAXED, __HIP_MEMORY_SCOPE_AGENT);
            }
            // poll all 4 regions (own included) -> next B image, coalesced
            unsigned int v0 = __hip_atomic_load(ms + t,        __ATOMIC_RELAXED, __HIP_MEMORY_SCOPE_AGENT);
            unsigned int v1 = __hip_atomic_load(ms + t + 512,  __ATOMIC_RELAXED, __HIP_MEMORY_SCOPE_AGENT);
            unsigned int v2 = __hip_atomic_load(ms + t + 1024, __ATOMIC_RELAXED, __HIP_MEMORY_SCOPE_AGENT);
            unsigned int v3 = __hip_atomic_load(ms + t + 1536, __ATOMIC_RELAXED, __HIP_MEMORY_SCOPE_AGENT);
            int guard = 0;
            while (v0 == 0xFFFFFFFFu && ++guard < (1 << 20))
                v0 = __hip_atomic_load(ms + t,        __ATOMIC_RELAXED, __HIP_MEMORY_SCOPE_AGENT);
            guard = 0;
            while (v1 == 0xFFFFFFFFu && ++guard < (1 << 20))
                v1 = __hip_atomic_load(ms + t + 512,  __ATOMIC_RELAXED, __HIP_MEMORY_SCOPE_AGENT);
            guard = 0;
            while (v2 == 0xFFFFFFFFu && ++guard < (1 << 20))
                v2 = __hip_atomic_load(ms + t + 1024, __ATOMIC_RELAXED, __HIP_MEMORY_SCOPE_AGENT);
            guard = 0;
            while (v3 == 0xFFFFFFFFu && ++guard < (1 << 20))
                v3 = __hip_atomic_load(ms + t + 1536, __ATOMIC_RELAXED, __HIP_MEMORY_SCOPE_AGENT);
            unsigned int* dst = BsU + (p ^ 1) * 2048;
            dst[t] = v0; dst[t + 512] = v1; dst[t + 1024] = v2; dst[t + 1536] = v3;
        }
        __syncthreads();
        p ^= 1;
        ga0 = na0; ga1 = na1; ga2 = na2; ga3 = na3;
        gb0 = nb0; gb1 = nb1; gb2 = nb2; gb3 = nb3;
        gp = gpn; hp += hstep;
    }
}

// ---------------------------------------------------------------------------
// Kernel C: feats[m, o] = concat(hf[m], hb[m]) . w_out[o, :] + b_out[o]
// ---------------------------------------------------------------------------
__global__ __launch_bounds__(256)
void feats_proj(const float* __restrict__ hf, const float* __restrict__ hb,
                const float* __restrict__ w_out, const float* __restrict__ b_out,
                float* __restrict__ feats)
{
    const int lane = threadIdx.x & 63;
    const int wv   = threadIdx.x >> 6;
    const int m    = blockIdx.x * 4 + wv;
    const int o    = lane & 15;
    const int qq   = lane >> 4;

    const float* hsrc = (qq < 2) ? (hf + (size_t)m * 256 + qq * 128)
                                 : (hb + (size_t)m * 256 + (qq - 2) * 128);
    const float4* h4 = (const float4*)hsrc;
    const float4* w4 = (const float4*)(w_out + o * 512 + qq * 128);

    float acc = 0.f;
    #pragma unroll
    for (int i = 0; i < 32; ++i) {
        float4 hv = h4[i], wvv = w4[i];
        acc = fmaf(hv.x, wvv.x, acc);
        acc = fmaf(hv.y, wvv.y, acc);
        acc = fmaf(hv.z, wvv.z, acc);
        acc = fmaf(hv.w, wvv.w, acc);
    }
    acc += __shfl_xor(acc, 16, 64);
    acc += __shfl_xor(acc, 32, 64);
    if (lane < 16) feats[(size_t)m * 16 + o] = acc + b_out[o];
}

// ---------------------------------------------------------------------------
// Kernel D: Viterbi + backtrace.
// ---------------------------------------------------------------------------
__global__ __launch_bounds__(64)
void viterbi(const float* __restrict__ feats, const float* __restrict__ trans,
             float* __restrict__ out)
{
    __shared__ unsigned char bp[T_][16];
    const int b    = blockIdx.x;
    const int lane = threadIdx.x;
    const int l15  = lane & 15;

    float tr[16];
    #pragma unroll
    for (int p = 0; p < 16; ++p)
        tr[p] = (lane < 16) ? trans[lane * 16 + p] : 0.f;

    float fv = (lane == START_) ? 0.f : NEG_;

    for (int t4 = 0; t4 < T_; t4 += 4) {
        float fblk = feats[((size_t)(t4 + (lane >> 4)) * 64 + b) * 16 + l15];
        #pragma unroll
        for (int tt = 0; tt < 4; ++tt) {
            const int t = t4 + tt;
            float best = -3.4e38f; int arg = 0;
            #pragma unroll
            for (int p = 0; p < 16; ++p) {
                float s = __shfl(fv, p, 64) + tr[p];
                if (s > best) { best = s; arg = p; }
            }
            float ft = __shfl(fblk, tt * 16 + l15, 64);
            if (lane < 16) {
                fv = best + ft;
                bp[t][lane] = (unsigned char)arg;
            }
        }
    }

    float term = fv + ((lane < 16) ? trans[STOP_ * 16 + lane] : 0.f);
    float v  = (lane < 16) ? term : -3.4e38f;
    int  idx = (lane < 16) ? lane : (1 << 20);
    #pragma unroll
    for (int off = 1; off < 64; off <<= 1) {
        float v2 = __shfl_xor(v, off, 64);
        int   i2 = __shfl_xor(idx, off, 64);
        if (v2 > v || (v2 == v && i2 < idx)) { v = v2; idx = i2; }
    }
    __syncthreads();
    if (lane == 0) {
        out[b] = v;
        int tag = idx;
        for (int t = T_ - 1; t >= 0; --t) {
            out[64 + (size_t)t * 64 + b] = (float)tag;
            tag = bp[t][tag];
        }
    }
}

// ---------------------------------------------------------------------------
extern "C" void kernel_launch(void* const* d_in, const int* in_sizes, int n_in,
                              void* d_out, int out_size, void* d_ws, size_t ws_size,
                              hipStream_t stream) {
    const int*   sentence = (const int*)d_in[0];
    const float* emb      = (const float*)d_in[1];
    const float* w_ih_f   = (const float*)d_in[2];
    const float* w_hh_f   = (const float*)d_in[3];
    const float* b_f      = (const float*)d_in[4];
    const float* w_ih_b   = (const float*)d_in[5];
    const float* w_hh_b   = (const float*)d_in[6];
    const float* b_b      = (const float*)d_in[7];
    const float* w_out    = (const float*)d_in[8];
    const float* b_out    = (const float*)d_in[9];
    const float* trans    = (const float*)d_in[10];
    float* out = (float*)d_out;

    // workspace: gin_f|gin_b (fp16 64MB ea) | hf|hb (fp32 32MB ea) |
    //            feats (2MB) | wih16 (1MB) | wregB (1MB) | mail (32MB)
    _Float16* gin_f = (_Float16*)d_ws;
    _Float16* gin_b = gin_f + (size_t)T_ * B_ * G_;
    float* hf    = (float*)(gin_b + (size_t)T_ * B_ * G_);
    float* hb    = hf + (size_t)T_ * B_ * H_;
    float* feats = hb + (size_t)T_ * B_ * H_;
    _Float16* wih16 = (_Float16*)(feats + (size_t)T_ * B_ * K_);
    _Float16* wregB = wih16 + 524288;
    unsigned int* mail = (unsigned int*)(wregB + 524288);

    prep_weights<<<512, 256, 0, stream>>>(w_hh_f, w_hh_b, w_ih_f, w_ih_b,
                                          wregB, wih16);
    gates_mfma<<<dim3(512, 2), 256, 0, stream>>>(sentence, emb, wih16,
                                                 b_f, b_b, gin_f, gin_b);
    hipMemsetAsync(mail, 0xFF, (size_t)33554432, stream);  // prime sentinels
    lstm_ring<<<32, 512, 0, stream>>>(gin_f, gin_b, wregB, hf, hb, mail);
    feats_proj<<<8192, 256, 0, stream>>>(hf, hb, w_out, b_out, feats);
    viterbi<<<64, 64, 0, stream>>>(feats, trans, out);
}